// Round 1
// baseline (758.886 us; speedup 1.0000x reference)
//
#include <hip/hip_runtime.h>

#define B_      64
#define C_      512
#define HW      32
#define NNODE   128
#define NEDGE   1024
#define NLAYERS 8
#define EPS_    1e-5f

#define TILE 64
#define KT   16

// ---------------- utility kernels ----------------

__global__ void zero_k(float* __restrict__ p, int n) {
    int i = blockIdx.x * 256 + threadIdx.x;
    if (i < n) p[i] = 0.0f;
}

__global__ void count_deg_k(const int* __restrict__ ei, float* __restrict__ deg) {
    int e = blockIdx.x * 256 + threadIdx.x;
    if (e < NEDGE) atomicAdd(&deg[ei[NEDGE + e]], 1.0f);   // dst row
}

__global__ void dinv_k(float* __restrict__ deg) {
    int n = threadIdx.x;                    // 128 threads
    float d = deg[n] + 1.0f;                // + self loop
    deg[n] = 1.0f / sqrtf(d);               // deg>0 guaranteed
}

__global__ void build_A_k(const int* __restrict__ ei, const float* __restrict__ dinv,
                          float* __restrict__ A) {
    int e = blockIdx.x * 256 + threadIdx.x;
    if (e < NEDGE) {
        int s = ei[e];
        int d = ei[NEDGE + e];
        atomicAdd(&A[d * NNODE + s], dinv[s] * dinv[d]);
    } else if (e < NEDGE + NNODE) {
        int n = e - NEDGE;
        atomicAdd(&A[n * NNODE + n], dinv[n] * dinv[n]);
    }
}

// ---------------- pool + pos_emb -> x (B,128,512) ----------------
// one block per (b,c) plane pair; 128 threads: t<64 rgb cell, t>=64 ir cell
__global__ void pool_pos_k(const float* __restrict__ rgb, const float* __restrict__ ir,
                           const float* __restrict__ pos, float* __restrict__ x) {
    int bc = blockIdx.x;            // b*512 + c
    int c  = bc & (C_ - 1);
    int b  = bc >> 9;
    int t  = threadIdx.x;           // 0..127
    int s    = t >> 6;              // 0 rgb / 1 ir (uniform per wave)
    int cell = t & 63;
    int va = cell >> 3, ha = cell & 7;

    const float* src = (s ? ir : rgb) + ((size_t)bc * HW + va * 4) * HW + ha * 4;
    float4 r0 = *(const float4*)(src);
    float4 r1 = *(const float4*)(src + HW);
    float4 r2 = *(const float4*)(src + 2 * HW);
    float4 r3 = *(const float4*)(src + 3 * HW);
    float sum = r0.x + r0.y + r0.z + r0.w
              + r1.x + r1.y + r1.z + r1.w
              + r2.x + r2.y + r2.z + r2.w
              + r3.x + r3.y + r3.z + r3.w;
    float avg = sum * (1.0f / 16.0f);

    int n = t;                       // node id: rgb cells 0..63 then ir 64..127
    x[((size_t)b * NNODE + n) * C_ + c] = avg + pos[n * C_ + c];
}

// ---------------- GEMM: Y[M,N] = X[M,K] @ W[K,N] ----------------
__global__ __launch_bounds__(256) void gemm_k(const float* __restrict__ X,
                                              const float* __restrict__ W,
                                              float* __restrict__ Y,
                                              int M, int N, int K) {
    __shared__ float sA[KT][TILE];
    __shared__ float sB[KT][TILE];
    const int bm = blockIdx.y * TILE;
    const int bn = blockIdx.x * TILE;
    const int tid = threadIdx.x;
    const int tx = tid & 15;            // n
    const int ty = tid >> 4;            // m
    const int ar = tid >> 2;            // 0..63 (row of A tile)
    const int ac = (tid & 3) << 2;      // 0,4,8,12
    const int br = tid >> 4;            // 0..15 (k row of B tile)
    const int bc = (tid & 15) << 2;

    float acc[4][4] = {};
    const float* Xp = X + (size_t)(bm + ar) * K + ac;
    const float* Wp = W + (size_t)br * N + bn + bc;

    for (int k0 = 0; k0 < K; k0 += KT) {
        float4 a = *(const float4*)(Xp + k0);
        float4 w = *(const float4*)(Wp + (size_t)k0 * N);
        sA[ac + 0][ar] = a.x; sA[ac + 1][ar] = a.y;
        sA[ac + 2][ar] = a.z; sA[ac + 3][ar] = a.w;
        *(float4*)&sB[br][bc] = w;
        __syncthreads();
#pragma unroll
        for (int k = 0; k < KT; ++k) {
            float4 av = *(const float4*)&sA[k][ty << 2];
            float4 bv = *(const float4*)&sB[k][tx << 2];
            float aa[4] = {av.x, av.y, av.z, av.w};
            float bb[4] = {bv.x, bv.y, bv.z, bv.w};
#pragma unroll
            for (int i = 0; i < 4; ++i)
#pragma unroll
                for (int j = 0; j < 4; ++j)
                    acc[i][j] += aa[i] * bb[j];
        }
        __syncthreads();
    }
#pragma unroll
    for (int i = 0; i < 4; ++i) {
        float4 v = make_float4(acc[i][0], acc[i][1], acc[i][2], acc[i][3]);
        *(float4*)&Y[(size_t)(bm + (ty << 2) + i) * N + bn + (tx << 2)] = v;
    }
}

// ---------------- batched agg GEMM: Y[b] = relu(A @ XW[b] + bias) ----------------
// M=128, K=128, N=512. grid (N/64, M/64=2, B)
__global__ __launch_bounds__(256) void gemm_agg_k(const float* __restrict__ A,
                                                  const float* __restrict__ XW,
                                                  const float* __restrict__ bias,
                                                  float* __restrict__ Y) {
    __shared__ float sA[KT][TILE];
    __shared__ float sB[KT][TILE];
    const int b  = blockIdx.z;
    const int bm = blockIdx.y * TILE;
    const int bn = blockIdx.x * TILE;
    const int tid = threadIdx.x;
    const int tx = tid & 15;
    const int ty = tid >> 4;
    const int ar = tid >> 2;
    const int ac = (tid & 3) << 2;
    const int br = tid >> 4;
    const int bc = (tid & 15) << 2;

    const float* X = XW + (size_t)b * NNODE * C_;
    float* Yb = Y + (size_t)b * NNODE * C_;

    float acc[4][4] = {};
    const float* Ap = A + (size_t)(bm + ar) * NNODE + ac;
    const float* Xp = X + (size_t)br * C_ + bn + bc;

    for (int k0 = 0; k0 < NNODE; k0 += KT) {
        float4 a = *(const float4*)(Ap + k0);
        float4 w = *(const float4*)(Xp + (size_t)k0 * C_);
        sA[ac + 0][ar] = a.x; sA[ac + 1][ar] = a.y;
        sA[ac + 2][ar] = a.z; sA[ac + 3][ar] = a.w;
        *(float4*)&sB[br][bc] = w;
        __syncthreads();
#pragma unroll
        for (int k = 0; k < KT; ++k) {
            float4 av = *(const float4*)&sA[k][ty << 2];
            float4 bv = *(const float4*)&sB[k][tx << 2];
            float aa[4] = {av.x, av.y, av.z, av.w};
            float bb[4] = {bv.x, bv.y, bv.z, bv.w};
#pragma unroll
            for (int i = 0; i < 4; ++i)
#pragma unroll
                for (int j = 0; j < 4; ++j)
                    acc[i][j] += aa[i] * bb[j];
        }
        __syncthreads();
    }
#pragma unroll
    for (int i = 0; i < 4; ++i) {
        float4 v;
        float b0 = bias[bn + (tx << 2) + 0];
        float b1 = bias[bn + (tx << 2) + 1];
        float b2 = bias[bn + (tx << 2) + 2];
        float b3 = bias[bn + (tx << 2) + 3];
        v.x = fmaxf(acc[i][0] + b0, 0.0f);
        v.y = fmaxf(acc[i][1] + b1, 0.0f);
        v.z = fmaxf(acc[i][2] + b2, 0.0f);
        v.w = fmaxf(acc[i][3] + b3, 0.0f);
        *(float4*)&Yb[(size_t)(bm + (ty << 2) + i) * C_ + bn + (tx << 2)] = v;
    }
}

// ---------------- LayerNorm + permuted write-out ----------------
// one wave per (b,n) row; out[s][b][c][p], p = n&63, s = n>>6
__global__ void ln_out_k(const float* __restrict__ x, const float* __restrict__ lw,
                         const float* __restrict__ lb, float* __restrict__ out) {
    int row = blockIdx.x;             // b*128 + n
    int b = row >> 7, n = row & 127;
    int t = threadIdx.x;              // 0..63
    const float* xr = x + (size_t)row * C_;

    float4 v0 = ((const float4*)xr)[t * 2];
    float4 v1 = ((const float4*)xr)[t * 2 + 1];
    float s = v0.x + v0.y + v0.z + v0.w + v1.x + v1.y + v1.z + v1.w;
#pragma unroll
    for (int off = 32; off; off >>= 1) s += __shfl_down(s, off);
    float mu = __shfl(s, 0) * (1.0f / C_);

    float d0x = v0.x - mu, d0y = v0.y - mu, d0z = v0.z - mu, d0w = v0.w - mu;
    float d1x = v1.x - mu, d1y = v1.y - mu, d1z = v1.z - mu, d1w = v1.w - mu;
    float sq = d0x * d0x + d0y * d0y + d0z * d0z + d0w * d0w
             + d1x * d1x + d1y * d1y + d1z * d1z + d1w * d1w;
#pragma unroll
    for (int off = 32; off; off >>= 1) sq += __shfl_down(sq, off);
    float var = __shfl(sq, 0) * (1.0f / C_);
    float inv = 1.0f / sqrtf(var + EPS_);

    int p = n & 63, sfl = n >> 6;
    size_t base = (size_t)sfl * (B_ * C_ * 64) + (size_t)b * (C_ * 64) + p;
    int c0 = t * 8;
    float dv[8] = {d0x, d0y, d0z, d0w, d1x, d1y, d1z, d1w};
#pragma unroll
    for (int j = 0; j < 8; ++j) {
        int c = c0 + j;
        out[base + (size_t)c * 64] = dv[j] * inv * lw[c] + lb[c];
    }
}

// ---------------- launch ----------------

extern "C" void kernel_launch(void* const* d_in, const int* in_sizes, int n_in,
                              void* d_out, int out_size, void* d_ws, size_t ws_size,
                              hipStream_t stream) {
    const float* rgb = (const float*)d_in[0];
    const float* ir  = (const float*)d_in[1];
    const int*   ei  = (const int*)d_in[2];
    const float* pos = (const float*)d_in[3];
    const float* Wg  = (const float*)d_in[4];
    const float* bg  = (const float*)d_in[5];
    const float* lw  = (const float*)d_in[6];
    const float* lb  = (const float*)d_in[7];
    float* out = (float*)d_out;

    float* ws  = (float*)d_ws;
    float* x   = ws;                              // B*128*512
    float* xw  = ws + (size_t)B_ * NNODE * C_;    // B*128*512
    float* A   = xw + (size_t)B_ * NNODE * C_;    // 128*128
    float* deg = A + NNODE * NNODE;               // 128 (becomes dinv)

    zero_k<<<(NNODE * NNODE + NNODE + 255) / 256, 256, 0, stream>>>(A, NNODE * NNODE + NNODE);
    count_deg_k<<<(NEDGE + 255) / 256, 256, 0, stream>>>(ei, deg);
    dinv_k<<<1, NNODE, 0, stream>>>(deg);
    build_A_k<<<(NEDGE + NNODE + 255) / 256, 256, 0, stream>>>(ei, deg, A);

    pool_pos_k<<<B_ * C_, 128, 0, stream>>>(rgb, ir, pos, x);

    for (int l = 0; l < NLAYERS; ++l) {
        gemm_k<<<dim3(C_ / TILE, (B_ * NNODE) / TILE), 256, 0, stream>>>(
            x, Wg + (size_t)l * C_ * C_, xw, B_ * NNODE, C_, C_);
        gemm_agg_k<<<dim3(C_ / TILE, NNODE / TILE, B_), 256, 0, stream>>>(
            A, xw, bg + (size_t)l * C_, x);
    }

    ln_out_k<<<B_ * NNODE, 64, 0, stream>>>(x, lw, lb, out);
}

// Round 2
// 413.055 us; speedup vs baseline: 1.8373x; 1.8373x over previous
//
#include <hip/hip_runtime.h>

#define B_      64
#define C_      512
#define NNODE   128
#define NEDGE   1024
#define NLAYERS 8
#define EPS_    1e-5f

typedef __attribute__((ext_vector_type(8))) short bf16x8;
typedef __attribute__((ext_vector_type(4))) float f32x4;

__device__ __forceinline__ ushort f2b(float x) {
    unsigned u = __builtin_bit_cast(unsigned, x);
    unsigned r = (u + 0x7fffu + ((u >> 16) & 1u)) >> 16;
    return (ushort)r;
}
__device__ __forceinline__ float b2f(ushort h) {
    unsigned u = ((unsigned)h) << 16;
    return __builtin_bit_cast(float, u);
}

// ---------------- graph prep ----------------

__global__ void zero_k(float* __restrict__ p, int n) {
    int i = blockIdx.x * 256 + threadIdx.x;
    if (i < n) p[i] = 0.0f;
}

__global__ void count_deg_k(const int* __restrict__ ei, float* __restrict__ deg) {
    int e = blockIdx.x * 256 + threadIdx.x;
    if (e < NEDGE) atomicAdd(&deg[ei[NEDGE + e]], 1.0f);
}

__global__ void dinv_k(float* __restrict__ deg) {
    int n = threadIdx.x;
    deg[n] = 1.0f / sqrtf(deg[n] + 1.0f);
}

__global__ void build_A_k(const int* __restrict__ ei, const float* __restrict__ dinv,
                          float* __restrict__ A) {
    int e = blockIdx.x * 256 + threadIdx.x;
    if (e < NEDGE) {
        int s = ei[e];
        int d = ei[NEDGE + e];
        atomicAdd(&A[d * NNODE + s], dinv[s] * dinv[d]);
    } else if (e < NEDGE + NNODE) {
        int n = e - NEDGE;
        atomicAdd(&A[n * NNODE + n], dinv[n] * dinv[n]);
    }
}

__global__ void splitA_k(const float* __restrict__ A, ushort* __restrict__ Ah,
                         ushort* __restrict__ Al) {
    int i = blockIdx.x * 256 + threadIdx.x;
    if (i < NNODE * NNODE) {
        float v = A[i];
        ushort h = f2b(v);
        Ah[i] = h;
        Al[i] = f2b(v - b2f(h));
    }
}

// ---------------- W transpose + split: WT[l][n][k] = W[l][k][n] ----------------
__global__ __launch_bounds__(256) void wprep_k(const float* __restrict__ W,
                                               ushort* __restrict__ WTh,
                                               ushort* __restrict__ WTl) {
    __shared__ float tl[64][68];
    const int t = threadIdx.x;
    const int n0 = blockIdx.x * 64, k0 = blockIdx.y * 64, l = blockIdx.z;
    const float* Wl = W + (size_t)l * C_ * C_;
    {
        int kk = t >> 2, nc = (t & 3) * 16;
        const float* src = Wl + (size_t)(k0 + kk) * C_ + n0 + nc;
#pragma unroll
        for (int g = 0; g < 4; ++g)
            *(float4*)&tl[kk][nc + g * 4] = *(const float4*)(src + g * 4);
    }
    __syncthreads();
    {
        int nn = t >> 2, kc = (t & 3) * 16;
        ushort h[16], lo[16];
#pragma unroll
        for (int j = 0; j < 16; ++j) {
            float v = tl[kc + j][nn];
            h[j] = f2b(v);
            lo[j] = f2b(v - b2f(h[j]));
        }
        size_t o = ((size_t)l * C_ + n0 + nn) * C_ + k0 + kc;
        *(int4*)&WTh[o] = *(int4*)&h[0];
        *(int4*)&WTh[o + 8] = *(int4*)&h[8];
        *(int4*)&WTl[o] = *(int4*)&lo[0];
        *(int4*)&WTl[o + 8] = *(int4*)&lo[8];
    }
}

// ---------------- fused pool + pos + split -> xh/xl [B*128][512] ----------------
// grid (8 ctiles, 64 b), 256 thr. LDS tile [cc][n].
__global__ __launch_bounds__(256) void pool_x_k(const float* __restrict__ rgb,
                                                const float* __restrict__ ir,
                                                const float* __restrict__ pos,
                                                ushort* __restrict__ xh,
                                                ushort* __restrict__ xl) {
    __shared__ float lds[64][132];
    const int t = threadIdx.x, lane = t & 63, wv = t >> 6;
    const int c0 = blockIdx.x * 64, b = blockIdx.y;

    // phase 1: pool 128 planes (2 src x 64 c), one plane per wave-iteration
    for (int i = 0; i < 32; ++i) {
        int pp = wv * 32 + i;
        int src = pp >> 6, cc = pp & 63;
        const float* base = (src ? ir : rgb) + ((size_t)(b * C_ + c0 + cc)) * 1024;
        const float* lp = base + lane * 16;   // lane: row = lane>>1, colhalf = lane&1
        float4 v0 = ((const float4*)lp)[0];
        float4 v1 = ((const float4*)lp)[1];
        float4 v2 = ((const float4*)lp)[2];
        float4 v3 = ((const float4*)lp)[3];
        float s0 = v0.x + v0.y + v0.z + v0.w;
        float s1 = v1.x + v1.y + v1.z + v1.w;
        float s2 = v2.x + v2.y + v2.z + v2.w;
        float s3 = v3.x + v3.y + v3.z + v3.w;
        s0 += __shfl_xor(s0, 2); s1 += __shfl_xor(s1, 2);
        s2 += __shfl_xor(s2, 2); s3 += __shfl_xor(s3, 2);
        s0 += __shfl_xor(s0, 4); s1 += __shfl_xor(s1, 4);
        s2 += __shfl_xor(s2, 4); s3 += __shfl_xor(s3, 4);
        if ((lane & 6) == 0) {
            int va = lane >> 3, ch = lane & 1;
            int n0 = src * 64 + va * 8 + ch * 4;
            *(float4*)&lds[cc][n0] = make_float4(s0 * 0.0625f, s1 * 0.0625f,
                                                 s2 * 0.0625f, s3 * 0.0625f);
        }
    }
    __syncthreads();

    // phase 2: row n, add pos, split, coalesced bf16 write
    const int n = t >> 1, half = t & 1;
    const int cb = half * 32;
    float v[32];
#pragma unroll
    for (int j = 0; j < 32; ++j)
        v[j] = lds[cb + j][n] + pos[(size_t)n * C_ + c0 + cb + j];
    ushort hs[32], ls[32];
#pragma unroll
    for (int j = 0; j < 32; ++j) {
        hs[j] = f2b(v[j]);
        ls[j] = f2b(v[j] - b2f(hs[j]));
    }
    size_t o = ((size_t)(b * NNODE + n)) * C_ + c0 + cb;
#pragma unroll
    for (int g = 0; g < 4; ++g) {
        *(int4*)&xh[o + g * 8] = *(int4*)&hs[g * 8];
        *(int4*)&xl[o + g * 8] = *(int4*)&ls[g * 8];
    }
}

// ---------------- split-3 MFMA GEMM ----------------
// MODE 0: XWT[b][n][m] = (X[b*128+m][:] @ WT[n][:]),  A=x (BM=128=one b), B=WT, K=512
//         out transposed (channel-major), grid (8, 64)
// MODE 1: x[b*128+m][n] = relu(Anorm[m][:] @ XWT[b][n][:] + bias[n]), K=128
//         grid (8, 1, 64)
template <int MODE>
__global__ __launch_bounds__(256) void gemm_split_k(
    const ushort* __restrict__ APh, const ushort* __restrict__ APl,
    const ushort* __restrict__ BPh, const ushort* __restrict__ BPl,
    ushort* __restrict__ Oh, ushort* __restrict__ Ol,
    const float* __restrict__ bias, int K) {
    __shared__ ushort sAh[128 * 40], sAl[128 * 40], sBh[64 * 40], sBl[64 * 40];
    const int t = threadIdx.x;
    const int lane = t & 63, wv = t >> 6;
    const int wm = wv >> 1, wn = wv & 1;
    const int lr = lane & 15, lq = lane >> 4;
    const int bn = blockIdx.x * 64;
    const int b = (MODE == 0) ? blockIdx.y : blockIdx.z;

    const ushort* Ah = APh + (MODE == 0 ? (size_t)b * NNODE * K : 0);
    const ushort* Al = APl + (MODE == 0 ? (size_t)b * NNODE * K : 0);
    const ushort* Bh = BPh + (MODE == 1 ? (size_t)b * C_ * K : 0) + (size_t)bn * K;
    const ushort* Bl = BPl + (MODE == 1 ? (size_t)b * C_ * K : 0) + (size_t)bn * K;

    const int ar = t >> 2, ak = (t & 3) * 8;   // A rows ar, ar+64
    const int br = t >> 2, bk = (t & 3) * 8;   // B rows 0..63

    f32x4 zero4 = {0.f, 0.f, 0.f, 0.f};
    f32x4 acc[4][2];
#pragma unroll
    for (int i = 0; i < 4; ++i)
#pragma unroll
        for (int j = 0; j < 2; ++j) acc[i][j] = zero4;

    int4 rA0h, rA1h, rA0l, rA1l, rB0h, rB0l;
#define GLOAD(K0)                                                          \
    {                                                                      \
        rA0h = *(const int4*)&Ah[(size_t)ar * K + (K0) + ak];              \
        rA1h = *(const int4*)&Ah[(size_t)(ar + 64) * K + (K0) + ak];       \
        rA0l = *(const int4*)&Al[(size_t)ar * K + (K0) + ak];              \
        rA1l = *(const int4*)&Al[(size_t)(ar + 64) * K + (K0) + ak];       \
        rB0h = *(const int4*)&Bh[(size_t)br * K + (K0) + bk];              \
        rB0l = *(const int4*)&Bl[(size_t)br * K + (K0) + bk];              \
    }

    GLOAD(0)
    for (int k0 = 0; k0 < K; k0 += 32) {
        __syncthreads();
        *(int4*)&sAh[ar * 40 + ak] = rA0h;
        *(int4*)&sAh[(ar + 64) * 40 + ak] = rA1h;
        *(int4*)&sAl[ar * 40 + ak] = rA0l;
        *(int4*)&sAl[(ar + 64) * 40 + ak] = rA1l;
        *(int4*)&sBh[br * 40 + bk] = rB0h;
        *(int4*)&sBl[br * 40 + bk] = rB0l;
        __syncthreads();
        if (k0 + 32 < K) GLOAD(k0 + 32)

        bf16x8 fah[4], fal[4], fbh[2], fbl[2];
#pragma unroll
        for (int mf = 0; mf < 4; ++mf) {
            int row = (wm * 64 + mf * 16 + lr) * 40 + lq * 8;
            fah[mf] = *(const bf16x8*)&sAh[row];
            fal[mf] = *(const bf16x8*)&sAl[row];
        }
#pragma unroll
        for (int nf = 0; nf < 2; ++nf) {
            int row = (wn * 32 + nf * 16 + lr) * 40 + lq * 8;
            fbh[nf] = *(const bf16x8*)&sBh[row];
            fbl[nf] = *(const bf16x8*)&sBl[row];
        }
#pragma unroll
        for (int mf = 0; mf < 4; ++mf)
#pragma unroll
            for (int nf = 0; nf < 2; ++nf) {
                acc[mf][nf] = __builtin_amdgcn_mfma_f32_16x16x32_bf16(
                    fah[mf], fbh[nf], acc[mf][nf], 0, 0, 0);
                acc[mf][nf] = __builtin_amdgcn_mfma_f32_16x16x32_bf16(
                    fal[mf], fbh[nf], acc[mf][nf], 0, 0, 0);
                acc[mf][nf] = __builtin_amdgcn_mfma_f32_16x16x32_bf16(
                    fah[mf], fbl[nf], acc[mf][nf], 0, 0, 0);
            }
    }

    // epilogue
    if (MODE == 0) {
        size_t bO = (size_t)b * C_ * NNODE;
#pragma unroll
        for (int mf = 0; mf < 4; ++mf)
#pragma unroll
            for (int nf = 0; nf < 2; ++nf) {
                int m0 = wm * 64 + mf * 16 + lq * 4;
                int nl = bn + wn * 32 + nf * 16 + lr;
                ushort hh[4], ll[4];
#pragma unroll
                for (int r = 0; r < 4; ++r) {
                    float x = acc[mf][nf][r];
                    hh[r] = f2b(x);
                    ll[r] = f2b(x - b2f(hh[r]));
                }
                *(ushort4*)&Oh[bO + (size_t)nl * NNODE + m0] = *(ushort4*)hh;
                *(ushort4*)&Ol[bO + (size_t)nl * NNODE + m0] = *(ushort4*)ll;
            }
    } else {
#pragma unroll
        for (int nf = 0; nf < 2; ++nf) {
            int nl = bn + wn * 32 + nf * 16 + lr;
            float bv = bias[nl];
#pragma unroll
            for (int mf = 0; mf < 4; ++mf) {
                int m0 = wm * 64 + mf * 16 + lq * 4;
#pragma unroll
                for (int r = 0; r < 4; ++r) {
                    float y = fmaxf(acc[mf][nf][r] + bv, 0.0f);
                    ushort h = f2b(y);
                    size_t o = ((size_t)(b * NNODE + m0 + r)) * C_ + nl;
                    Oh[o] = h;
                    Ol[o] = f2b(y - b2f(h));
                }
            }
        }
    }
#undef GLOAD
}

// ---------------- LayerNorm + transposed write-out ----------------
// grid 128 = (s,b); out[s][b][c][p]
__global__ __launch_bounds__(256) void ln_out_k(const ushort* __restrict__ xh,
                                                const ushort* __restrict__ xl,
                                                const float* __restrict__ lw,
                                                const float* __restrict__ lb,
                                                float* __restrict__ out) {
    __shared__ float tile[64][68];
    __shared__ float muA[64], invA[64];
    const int t = threadIdx.x, lane = t & 63, wv = t >> 6;
    const int s = blockIdx.x >> 6, b = blockIdx.x & 63;

    // stats: wave wv handles rows p = wv*16 .. +15
    for (int i = 0; i < 16; ++i) {
        int p = wv * 16 + i;
        size_t row = ((size_t)(b * NNODE + s * 64 + p)) * C_;
        int c = lane * 8;
        int4 hh = *(const int4*)&xh[row + c];
        int4 llv = *(const int4*)&xl[row + c];
        ushort* hp = (ushort*)&hh;
        ushort* lp = (ushort*)&llv;
        float s1 = 0.f, s2 = 0.f;
#pragma unroll
        for (int j = 0; j < 8; ++j) {
            float v = b2f(hp[j]) + b2f(lp[j]);
            s1 += v;
            s2 += v * v;
        }
#pragma unroll
        for (int off = 32; off; off >>= 1) {
            s1 += __shfl_xor(s1, off);
            s2 += __shfl_xor(s2, off);
        }
        if (lane == 0) {
            float mu = s1 * (1.0f / C_);
            muA[p] = mu;
            invA[p] = rsqrtf(s2 * (1.0f / C_) - mu * mu + EPS_);
        }
    }
    __syncthreads();

    size_t ob = (size_t)s * (B_ * C_ * 64) + (size_t)b * (C_ * 64);
    for (int ct = 0; ct < 8; ++ct) {
        {
            int p = t >> 2, cp = (t & 3) * 16;
            size_t row = ((size_t)(b * NNODE + s * 64 + p)) * C_ + ct * 64 + cp;
            int4 h0 = *(const int4*)&xh[row];
            int4 h1 = *(const int4*)&xh[row + 8];
            int4 l0 = *(const int4*)&xl[row];
            int4 l1 = *(const int4*)&xl[row + 8];
            ushort* hp0 = (ushort*)&h0;
            ushort* hp1 = (ushort*)&h1;
            ushort* lp0 = (ushort*)&l0;
            ushort* lp1 = (ushort*)&l1;
#pragma unroll
            for (int j = 0; j < 8; ++j) tile[p][cp + j] = b2f(hp0[j]) + b2f(lp0[j]);
#pragma unroll
            for (int j = 0; j < 8; ++j) tile[p][cp + 8 + j] = b2f(hp1[j]) + b2f(lp1[j]);
        }
        __syncthreads();
        {
            int p = t & 63, cr = t >> 6;
            float mu = muA[p], inv = invA[p];
#pragma unroll
            for (int k2 = 0; k2 < 16; ++k2) {
                int cl = cr + k2 * 4;
                int c = ct * 64 + cl;
                float v = (tile[p][cl] - mu) * inv * lw[c] + lb[c];
                out[ob + (size_t)c * 64 + p] = v;
            }
        }
        __syncthreads();
    }
}

// ---------------- launch ----------------

extern "C" void kernel_launch(void* const* d_in, const int* in_sizes, int n_in,
                              void* d_out, int out_size, void* d_ws, size_t ws_size,
                              hipStream_t stream) {
    const float* rgb = (const float*)d_in[0];
    const float* ir  = (const float*)d_in[1];
    const int*   ei  = (const int*)d_in[2];
    const float* pos = (const float*)d_in[3];
    const float* Wg  = (const float*)d_in[4];
    const float* bg  = (const float*)d_in[5];
    const float* lw  = (const float*)d_in[6];
    const float* lb  = (const float*)d_in[7];
    float* out = (float*)d_out;

    char* ws = (char*)d_ws;
    ushort* xh   = (ushort*)(ws);
    ushort* xl   = (ushort*)(ws + 8388608);
    ushort* xwTh = (ushort*)(ws + 16777216);
    ushort* xwTl = (ushort*)(ws + 25165824);
    ushort* WTh  = (ushort*)(ws + 33554432);
    ushort* WTl  = (ushort*)(ws + 37748736);
    float*  Afp  = (float*)(ws + 41943040);
    float*  deg  = Afp + NNODE * NNODE;
    ushort* Ahn  = (ushort*)(ws + 42009088);
    ushort* Aln  = (ushort*)(ws + 42041856);

    zero_k<<<(NNODE * NNODE + NNODE + 255) / 256, 256, 0, stream>>>(Afp, NNODE * NNODE + NNODE);
    count_deg_k<<<(NEDGE + 255) / 256, 256, 0, stream>>>(ei, deg);
    dinv_k<<<1, NNODE, 0, stream>>>(deg);
    build_A_k<<<(NEDGE + NNODE + 255) / 256, 256, 0, stream>>>(ei, deg, Afp);
    splitA_k<<<(NNODE * NNODE + 255) / 256, 256, 0, stream>>>(Afp, Ahn, Aln);

    wprep_k<<<dim3(8, 8, NLAYERS), 256, 0, stream>>>(Wg, WTh, WTl);
    pool_x_k<<<dim3(8, B_), 256, 0, stream>>>(rgb, ir, pos, xh, xl);

    for (int l = 0; l < NLAYERS; ++l) {
        gemm_split_k<0><<<dim3(8, B_), 256, 0, stream>>>(
            xh, xl, WTh + (size_t)l * C_ * C_, WTl + (size_t)l * C_ * C_,
            xwTh, xwTl, nullptr, C_);
        gemm_split_k<1><<<dim3(8, 1, B_), 256, 0, stream>>>(
            Ahn, Aln, xwTh, xwTl, xh, xl, bg + (size_t)l * C_, NNODE);
    }

    ln_out_k<<<2 * B_, 256, 0, stream>>>(xh, xl, lw, lb, out);
}

// Round 3
// 362.745 us; speedup vs baseline: 2.0921x; 1.1387x over previous
//
#include <hip/hip_runtime.h>

#define B_      64
#define C_      512
#define NNODE   128
#define NEDGE   1024
#define NLAYERS 8
#define EPS_    1e-5f

typedef __attribute__((ext_vector_type(8))) short bf16x8;
typedef __attribute__((ext_vector_type(4))) float f32x4;

__device__ __forceinline__ ushort f2b(float x) {
    unsigned u = __builtin_bit_cast(unsigned, x);
    unsigned r = (u + 0x7fffu + ((u >> 16) & 1u)) >> 16;
    return (ushort)r;
}
__device__ __forceinline__ float b2f(ushort h) {
    unsigned u = ((unsigned)h) << 16;
    return __builtin_bit_cast(float, u);
}

// ---------------- graph prep ----------------

__global__ void zero_k(float* __restrict__ p, int n) {
    int i = blockIdx.x * 256 + threadIdx.x;
    if (i < n) p[i] = 0.0f;
}

__global__ void count_deg_k(const int* __restrict__ ei, float* __restrict__ deg) {
    int e = blockIdx.x * 256 + threadIdx.x;
    if (e < NEDGE) atomicAdd(&deg[ei[NEDGE + e]], 1.0f);
}

__global__ void dinv_k(float* __restrict__ deg) {
    int n = threadIdx.x;
    deg[n] = 1.0f / sqrtf(deg[n] + 1.0f);
}

__global__ void build_A_k(const int* __restrict__ ei, const float* __restrict__ dinv,
                          float* __restrict__ A) {
    int e = blockIdx.x * 256 + threadIdx.x;
    if (e < NEDGE) {
        int s = ei[e];
        int d = ei[NEDGE + e];
        atomicAdd(&A[d * NNODE + s], dinv[s] * dinv[d]);
    } else if (e < NEDGE + NNODE) {
        int n = e - NEDGE;
        atomicAdd(&A[n * NNODE + n], dinv[n] * dinv[n]);
    }
}

__global__ void splitA_k(const float* __restrict__ A, ushort* __restrict__ Ah,
                         ushort* __restrict__ Al) {
    int i = blockIdx.x * 256 + threadIdx.x;
    if (i < NNODE * NNODE) {
        float v = A[i];
        ushort h = f2b(v);
        Ah[i] = h;
        Al[i] = f2b(v - b2f(h));
    }
}

// ---------------- W transpose + split: WT[l][n][k] = W[l][k][n] ----------------
__global__ __launch_bounds__(256) void wprep_k(const float* __restrict__ W,
                                               ushort* __restrict__ WTh,
                                               ushort* __restrict__ WTl) {
    __shared__ float tl[64][68];
    const int t = threadIdx.x;
    const int n0 = blockIdx.x * 64, k0 = blockIdx.y * 64, l = blockIdx.z;
    const float* Wl = W + (size_t)l * C_ * C_;
    {
        int kk = t >> 2, nc = (t & 3) * 16;
        const float* src = Wl + (size_t)(k0 + kk) * C_ + n0 + nc;
#pragma unroll
        for (int g = 0; g < 4; ++g)
            *(float4*)&tl[kk][nc + g * 4] = *(const float4*)(src + g * 4);
    }
    __syncthreads();
    {
        int nn = t >> 2, kc = (t & 3) * 16;
        ushort h[16], lo[16];
#pragma unroll
        for (int j = 0; j < 16; ++j) {
            float v = tl[kc + j][nn];
            h[j] = f2b(v);
            lo[j] = f2b(v - b2f(h[j]));
        }
        size_t o = ((size_t)l * C_ + n0 + nn) * C_ + k0 + kc;
        *(int4*)&WTh[o] = *(int4*)&h[0];
        *(int4*)&WTh[o + 8] = *(int4*)&h[8];
        *(int4*)&WTl[o] = *(int4*)&lo[0];
        *(int4*)&WTl[o + 8] = *(int4*)&lo[8];
    }
}

// ---------------- fused pool + pos + split -> x0 ----------------
// 16 channels per block, grid (32, 64) = 2048 blocks
__global__ __launch_bounds__(256) void pool_x_k(const float* __restrict__ rgb,
                                                const float* __restrict__ ir,
                                                const float* __restrict__ pos,
                                                ushort* __restrict__ xh,
                                                ushort* __restrict__ xl) {
    __shared__ float lds[16][132];
    const int t = threadIdx.x, lane = t & 63, wv = t >> 6;
    const int c0 = blockIdx.x * 16, b = blockIdx.y;

    for (int i = 0; i < 8; ++i) {
        int pp = wv * 8 + i;
        int src = pp >> 4, cc = pp & 15;
        const float* base = (src ? ir : rgb) + ((size_t)(b * C_ + c0 + cc)) * 1024;
        const float* lp = base + lane * 16;
        float4 v0 = ((const float4*)lp)[0];
        float4 v1 = ((const float4*)lp)[1];
        float4 v2 = ((const float4*)lp)[2];
        float4 v3 = ((const float4*)lp)[3];
        float s0 = v0.x + v0.y + v0.z + v0.w;
        float s1 = v1.x + v1.y + v1.z + v1.w;
        float s2 = v2.x + v2.y + v2.z + v2.w;
        float s3 = v3.x + v3.y + v3.z + v3.w;
        s0 += __shfl_xor(s0, 2); s1 += __shfl_xor(s1, 2);
        s2 += __shfl_xor(s2, 2); s3 += __shfl_xor(s3, 2);
        s0 += __shfl_xor(s0, 4); s1 += __shfl_xor(s1, 4);
        s2 += __shfl_xor(s2, 4); s3 += __shfl_xor(s3, 4);
        if ((lane & 6) == 0) {
            int va = lane >> 3, ch = lane & 1;
            int n0 = src * 64 + va * 8 + ch * 4;
            *(float4*)&lds[cc][n0] = make_float4(s0 * 0.0625f, s1 * 0.0625f,
                                                 s2 * 0.0625f, s3 * 0.0625f);
        }
    }
    __syncthreads();

    const int n = t >> 1, half = t & 1;
    const int cb = half * 8;
    float4 p0 = *(const float4*)&pos[(size_t)n * C_ + c0 + cb];
    float4 p1 = *(const float4*)&pos[(size_t)n * C_ + c0 + cb + 4];
    float v[8];
    v[0] = lds[cb + 0][n] + p0.x; v[1] = lds[cb + 1][n] + p0.y;
    v[2] = lds[cb + 2][n] + p0.z; v[3] = lds[cb + 3][n] + p0.w;
    v[4] = lds[cb + 4][n] + p1.x; v[5] = lds[cb + 5][n] + p1.y;
    v[6] = lds[cb + 6][n] + p1.z; v[7] = lds[cb + 7][n] + p1.w;
    ushort hs[8], ls[8];
#pragma unroll
    for (int j = 0; j < 8; ++j) {
        hs[j] = f2b(v[j]);
        ls[j] = f2b(v[j] - b2f(hs[j]));
    }
    size_t o = ((size_t)(b * NNODE + n)) * C_ + c0 + cb;
    *(int4*)&xh[o] = *(int4*)&hs[0];
    *(int4*)&xl[o] = *(int4*)&ls[0];
}

// ---------------- fused layer: x' = relu(A @ (x @ W) + bias) ----------------
// grid (4 n-tiles of 128, 64 b). block 256 thr = 4 waves (2x2), wave-tile 64x64.
__global__ __launch_bounds__(256) void gemm_fused_k(
    const ushort* __restrict__ Xh, const ushort* __restrict__ Xl,
    const ushort* __restrict__ Wh, const ushort* __restrict__ Wl,
    const ushort* __restrict__ Agh, const ushort* __restrict__ Agl,
    const float* __restrict__ bias,
    ushort* __restrict__ Yh, ushort* __restrict__ Yl) {
    __shared__ __align__(16) char smem[65536];
    ushort* sXh = (ushort*)smem;                 // [128][40]
    ushort* sXl = (ushort*)(smem + 10240);
    ushort* sWh = (ushort*)(smem + 20480);
    ushort* sWl = (ushort*)(smem + 30720);
    ushort* sPh = (ushort*)smem;                 // [128 n][128 m] granule-swizzled
    ushort* sPl = (ushort*)(smem + 32768);
    float*  sT  = (float*)smem;                  // [128][68] half-tile

    const int t = threadIdx.x;
    const int lane = t & 63;
    const int wv = t >> 6, wm = wv >> 1, wn = wv & 1;
    const int lr = lane & 15, lq = lane >> 4;
    const int bn = blockIdx.x * 128;
    const int b  = blockIdx.y;

    const ushort* xh = Xh + (size_t)b * NNODE * C_;
    const ushort* xl = Xl + (size_t)b * NNODE * C_;

    const int sr = t >> 1;            // staging row 0..127
    const int sk = (t & 1) * 16;      // staging k-offset (ushorts)

    f32x4 acc[4][4];
#pragma unroll
    for (int i = 0; i < 4; ++i)
#pragma unroll
        for (int j = 0; j < 4; ++j) acc[i][j] = (f32x4){0.f, 0.f, 0.f, 0.f};

    float bv[4];
#pragma unroll
    for (int nf = 0; nf < 4; ++nf) bv[nf] = bias[bn + wn * 64 + nf * 16 + lr];

    int4 rXh0, rXh1, rXl0, rXl1, rWh0, rWh1, rWl0, rWl1;
#define GLOAD(K0)                                                       \
    {                                                                   \
        rXh0 = *(const int4*)&xh[(size_t)sr * C_ + (K0) + sk];          \
        rXh1 = *(const int4*)&xh[(size_t)sr * C_ + (K0) + sk + 8];      \
        rXl0 = *(const int4*)&xl[(size_t)sr * C_ + (K0) + sk];          \
        rXl1 = *(const int4*)&xl[(size_t)sr * C_ + (K0) + sk + 8];      \
        rWh0 = *(const int4*)&Wh[(size_t)(bn + sr) * C_ + (K0) + sk];   \
        rWh1 = *(const int4*)&Wh[(size_t)(bn + sr) * C_ + (K0) + sk + 8]; \
        rWl0 = *(const int4*)&Wl[(size_t)(bn + sr) * C_ + (K0) + sk];   \
        rWl1 = *(const int4*)&Wl[(size_t)(bn + sr) * C_ + (K0) + sk + 8]; \
    }

    GLOAD(0)
    for (int k0 = 0; k0 < C_; k0 += 32) {
        __syncthreads();
        *(int4*)&sXh[sr * 40 + sk] = rXh0;
        *(int4*)&sXh[sr * 40 + sk + 8] = rXh1;
        *(int4*)&sXl[sr * 40 + sk] = rXl0;
        *(int4*)&sXl[sr * 40 + sk + 8] = rXl1;
        *(int4*)&sWh[sr * 40 + sk] = rWh0;
        *(int4*)&sWh[sr * 40 + sk + 8] = rWh1;
        *(int4*)&sWl[sr * 40 + sk] = rWl0;
        *(int4*)&sWl[sr * 40 + sk + 8] = rWl1;
        __syncthreads();
        if (k0 + 32 < C_) GLOAD(k0 + 32)

        bf16x8 fah[4], fal[4], fbh[4], fbl[4];
#pragma unroll
        for (int mf = 0; mf < 4; ++mf) {
            int ro = (wm * 64 + mf * 16 + lr) * 40 + lq * 8;
            fah[mf] = *(const bf16x8*)&sXh[ro];
            fal[mf] = *(const bf16x8*)&sXl[ro];
        }
#pragma unroll
        for (int nf = 0; nf < 4; ++nf) {
            int ro = (wn * 64 + nf * 16 + lr) * 40 + lq * 8;
            fbh[nf] = *(const bf16x8*)&sWh[ro];
            fbl[nf] = *(const bf16x8*)&sWl[ro];
        }
#pragma unroll
        for (int mf = 0; mf < 4; ++mf)
#pragma unroll
            for (int nf = 0; nf < 4; ++nf) {
                acc[mf][nf] = __builtin_amdgcn_mfma_f32_16x16x32_bf16(
                    fah[mf], fbh[nf], acc[mf][nf], 0, 0, 0);
                acc[mf][nf] = __builtin_amdgcn_mfma_f32_16x16x32_bf16(
                    fal[mf], fbh[nf], acc[mf][nf], 0, 0, 0);
                acc[mf][nf] = __builtin_amdgcn_mfma_f32_16x16x32_bf16(
                    fah[mf], fbl[nf], acc[mf][nf], 0, 0, 0);
            }
    }
#undef GLOAD

    // ---- epilogue-1: acc (XW tile, rows m, cols n) -> sP[n][m] swizzled bf16 pair
    __syncthreads();
#pragma unroll
    for (int mf = 0; mf < 4; ++mf) {
        int gm = wm * 8 + mf * 2 + (lq >> 1);
        int moff = (lq & 1) * 4;
#pragma unroll
        for (int nf = 0; nf < 4; ++nf) {
            int n = wn * 64 + nf * 16 + lr;
            int addr = n * 128 + ((gm ^ (n & 15)) << 3) + moff;
            ushort4 hu, lu;
            float y0 = acc[mf][nf][0], y1 = acc[mf][nf][1];
            float y2 = acc[mf][nf][2], y3 = acc[mf][nf][3];
            hu.x = f2b(y0); lu.x = f2b(y0 - b2f(hu.x));
            hu.y = f2b(y1); lu.y = f2b(y1 - b2f(hu.y));
            hu.z = f2b(y2); lu.z = f2b(y2 - b2f(hu.z));
            hu.w = f2b(y3); lu.w = f2b(y3 - b2f(hu.w));
            *(ushort4*)&sPh[addr] = hu;
            *(ushort4*)&sPl[addr] = lu;
        }
    }
    __syncthreads();

    // ---- stage 2: acc2 = A(128x128) @ XW(tile), K = 128 nodes
    f32x4 acc2[4][4];
#pragma unroll
    for (int i = 0; i < 4; ++i)
#pragma unroll
        for (int j = 0; j < 4; ++j) acc2[i][j] = (f32x4){0.f, 0.f, 0.f, 0.f};

    for (int kk = 0; kk < 4; ++kk) {
        bf16x8 gah[4], gal[4], gbh[4], gbl[4];
#pragma unroll
        for (int mf = 0; mf < 4; ++mf) {
            int row = wm * 64 + mf * 16 + lr;
            gah[mf] = *(const bf16x8*)&Agh[row * NNODE + kk * 32 + lq * 8];
            gal[mf] = *(const bf16x8*)&Agl[row * NNODE + kk * 32 + lq * 8];
        }
#pragma unroll
        for (int nf = 0; nf < 4; ++nf) {
            int n = wn * 64 + nf * 16 + lr;
            int g = (((kk * 4 + lq) ^ (n & 15)) << 3);
            gbh[nf] = *(const bf16x8*)&sPh[n * 128 + g];
            gbl[nf] = *(const bf16x8*)&sPl[n * 128 + g];
        }
#pragma unroll
        for (int mf = 0; mf < 4; ++mf)
#pragma unroll
            for (int nf = 0; nf < 4; ++nf) {
                acc2[mf][nf] = __builtin_amdgcn_mfma_f32_16x16x32_bf16(
                    gah[mf], gbh[nf], acc2[mf][nf], 0, 0, 0);
                acc2[mf][nf] = __builtin_amdgcn_mfma_f32_16x16x32_bf16(
                    gal[mf], gbh[nf], acc2[mf][nf], 0, 0, 0);
                acc2[mf][nf] = __builtin_amdgcn_mfma_f32_16x16x32_bf16(
                    gah[mf], gbl[nf], acc2[mf][nf], 0, 0, 0);
            }
    }

    // ---- bias + relu + transpose epilogue, two n-halves of 64
    for (int h = 0; h < 2; ++h) {
        __syncthreads();
        if (wn == h) {
#pragma unroll
            for (int mf = 0; mf < 4; ++mf)
#pragma unroll
                for (int nf = 0; nf < 4; ++nf) {
                    int mb = wm * 64 + mf * 16 + lq * 4;
                    int nn = nf * 16 + lr;
#pragma unroll
                    for (int r = 0; r < 4; ++r) {
                        float y = fmaxf(acc2[mf][nf][r] + bv[nf], 0.0f);
                        sT[(mb + r) * 68 + nn] = y;
                    }
                }
        }
        __syncthreads();
        {
            const int m = t >> 1, hw = t & 1;
            const float* rp = &sT[m * 68 + hw * 32];
            ushort hs[32], ls[32];
#pragma unroll
            for (int j = 0; j < 32; ++j) {
                float y = rp[j];
                hs[j] = f2b(y);
                ls[j] = f2b(y - b2f(hs[j]));
            }
            size_t o = ((size_t)(b * NNODE + m)) * C_ + bn + h * 64 + hw * 32;
#pragma unroll
            for (int g = 0; g < 4; ++g) {
                *(int4*)&Yh[o + g * 8] = *(int4*)&hs[g * 8];
                *(int4*)&Yl[o + g * 8] = *(int4*)&ls[g * 8];
            }
        }
    }
}

// ---------------- LayerNorm + transposed write-out ----------------
__global__ __launch_bounds__(256) void ln_out_k(const ushort* __restrict__ xh,
                                                const ushort* __restrict__ xl,
                                                const float* __restrict__ lw,
                                                const float* __restrict__ lb,
                                                float* __restrict__ out) {
    __shared__ float tile[64][68];
    __shared__ float muA[64], invA[64];
    const int t = threadIdx.x, lane = t & 63, wv = t >> 6;
    const int s = blockIdx.x >> 6, b = blockIdx.x & 63;

    for (int i = 0; i < 16; ++i) {
        int p = wv * 16 + i;
        size_t row = ((size_t)(b * NNODE + s * 64 + p)) * C_;
        int c = lane * 8;
        int4 hh = *(const int4*)&xh[row + c];
        int4 llv = *(const int4*)&xl[row + c];
        ushort* hp = (ushort*)&hh;
        ushort* lp = (ushort*)&llv;
        float s1 = 0.f, s2 = 0.f;
#pragma unroll
        for (int j = 0; j < 8; ++j) {
            float v = b2f(hp[j]) + b2f(lp[j]);
            s1 += v;
            s2 += v * v;
        }
#pragma unroll
        for (int off = 32; off; off >>= 1) {
            s1 += __shfl_xor(s1, off);
            s2 += __shfl_xor(s2, off);
        }
        if (lane == 0) {
            float mu = s1 * (1.0f / C_);
            muA[p] = mu;
            invA[p] = rsqrtf(s2 * (1.0f / C_) - mu * mu + EPS_);
        }
    }
    __syncthreads();

    size_t ob = (size_t)s * (B_ * C_ * 64) + (size_t)b * (C_ * 64);
    for (int ct = 0; ct < 8; ++ct) {
        {
            int p = t >> 2, cp = (t & 3) * 16;
            size_t row = ((size_t)(b * NNODE + s * 64 + p)) * C_ + ct * 64 + cp;
            int4 h0 = *(const int4*)&xh[row];
            int4 h1 = *(const int4*)&xh[row + 8];
            int4 l0 = *(const int4*)&xl[row];
            int4 l1 = *(const int4*)&xl[row + 8];
            ushort* hp0 = (ushort*)&h0;
            ushort* hp1 = (ushort*)&h1;
            ushort* lp0 = (ushort*)&l0;
            ushort* lp1 = (ushort*)&l1;
#pragma unroll
            for (int j = 0; j < 8; ++j) tile[p][cp + j] = b2f(hp0[j]) + b2f(lp0[j]);
#pragma unroll
            for (int j = 0; j < 8; ++j) tile[p][cp + 8 + j] = b2f(hp1[j]) + b2f(lp1[j]);
        }
        __syncthreads();
        {
            int p = t & 63, cr = t >> 6;
            float mu = muA[p], inv = invA[p];
#pragma unroll
            for (int k2 = 0; k2 < 16; ++k2) {
                int cl = cr + k2 * 4;
                int c = ct * 64 + cl;
                float v = (tile[p][cl] - mu) * inv * lw[c] + lb[c];
                out[ob + (size_t)c * 64 + p] = v;
            }
        }
        __syncthreads();
    }
}

// ---------------- launch ----------------

extern "C" void kernel_launch(void* const* d_in, const int* in_sizes, int n_in,
                              void* d_out, int out_size, void* d_ws, size_t ws_size,
                              hipStream_t stream) {
    const float* rgb = (const float*)d_in[0];
    const float* ir  = (const float*)d_in[1];
    const int*   ei  = (const int*)d_in[2];
    const float* pos = (const float*)d_in[3];
    const float* Wg  = (const float*)d_in[4];
    const float* bg  = (const float*)d_in[5];
    const float* lw  = (const float*)d_in[6];
    const float* lb  = (const float*)d_in[7];
    float* out = (float*)d_out;

    char* ws = (char*)d_ws;
    ushort* x0h  = (ushort*)(ws);
    ushort* x0l  = (ushort*)(ws + 8388608);
    ushort* x1h  = (ushort*)(ws + 16777216);
    ushort* x1l  = (ushort*)(ws + 25165824);
    ushort* WTh  = (ushort*)(ws + 33554432);
    ushort* WTl  = (ushort*)(ws + 37748736);
    float*  Afp  = (float*)(ws + 41943040);
    float*  deg  = Afp + NNODE * NNODE;
    ushort* Ahn  = (ushort*)(ws + 42009088);
    ushort* Aln  = (ushort*)(ws + 42041856);

    zero_k<<<(NNODE * NNODE + NNODE + 255) / 256, 256, 0, stream>>>(Afp, NNODE * NNODE + NNODE);
    count_deg_k<<<(NEDGE + 255) / 256, 256, 0, stream>>>(ei, deg);
    dinv_k<<<1, NNODE, 0, stream>>>(deg);
    build_A_k<<<(NEDGE + NNODE + 255) / 256, 256, 0, stream>>>(ei, deg, Afp);
    splitA_k<<<(NNODE * NNODE + 255) / 256, 256, 0, stream>>>(Afp, Ahn, Aln);

    wprep_k<<<dim3(8, 8, NLAYERS), 256, 0, stream>>>(Wg, WTh, WTl);
    pool_x_k<<<dim3(32, B_), 256, 0, stream>>>(rgb, ir, pos, x0h, x0l);

    for (int l = 0; l < NLAYERS; ++l) {
        const ushort* inh = (l & 1) ? x1h : x0h;
        const ushort* inl = (l & 1) ? x1l : x0l;
        ushort* outh = (l & 1) ? x0h : x1h;
        ushort* outl = (l & 1) ? x0l : x1l;
        gemm_fused_k<<<dim3(4, B_), 256, 0, stream>>>(
            inh, inl, WTh + (size_t)l * C_ * C_, WTl + (size_t)l * C_ * C_,
            Ahn, Aln, bg + (size_t)l * C_, outh, outl);
    }

    ln_out_k<<<2 * B_, 256, 0, stream>>>(x0h, x0l, lw, lb, out);
}